// Round 1
// baseline (44.045 us; speedup 1.0000x reference)
//
#include <hip/hip_runtime.h>
#include <cmath>

#define NROWS 524288
#define EPS 1e-10f

__device__ __forceinline__ float head_loss(const float* __restrict__ x, int n,
                                           const float* __restrict__ lbl) {
    float m = -INFINITY;
    #pragma unroll
    for (int i = 0; i < n; ++i) m = fmaxf(m, x[i]);
    float e[9];
    float s = 0.f;
    #pragma unroll
    for (int i = 0; i < n; ++i) { e[i] = __expf(x[i] - m); s += e[i]; }
    float inv = 1.0f / s;
    float acc = 0.f;
    #pragma unroll
    for (int i = 0; i < n; ++i) acc += __logf(e[i] * inv + EPS) * lbl[i];
    return -acc;
}

__global__ __launch_bounds__(256) void fused_loss_kernel(
    const float* __restrict__ o1, const float* __restrict__ o2,
    const float* __restrict__ o3, const float* __restrict__ o4,
    const float* __restrict__ lbl, double* __restrict__ acc_out) {
    const size_t i = (size_t)blockIdx.x * 256 + threadIdx.x;

    float loss = 0.f;
    if (i < NROWS) {
        // head 1: 8 floats, 32B row stride -> 16B aligned, two float4
        float v1[8];
        {
            const float4* p = reinterpret_cast<const float4*>(o1 + i * 8);
            float4 a = p[0], b = p[1];
            v1[0] = a.x; v1[1] = a.y; v1[2] = a.z; v1[3] = a.w;
            v1[4] = b.x; v1[5] = b.y; v1[6] = b.z; v1[7] = b.w;
        }
        // heads 2,3: 6 floats, 24B stride -> 8B aligned, three float2
        float v2[6], v3[6];
        {
            const float2* p = reinterpret_cast<const float2*>(o2 + i * 6);
            float2 a = p[0], b = p[1], c = p[2];
            v2[0] = a.x; v2[1] = a.y; v2[2] = b.x; v2[3] = b.y; v2[4] = c.x; v2[5] = c.y;
        }
        {
            const float2* p = reinterpret_cast<const float2*>(o3 + i * 6);
            float2 a = p[0], b = p[1], c = p[2];
            v3[0] = a.x; v3[1] = a.y; v3[2] = b.x; v3[3] = b.y; v3[4] = c.x; v3[5] = c.y;
        }
        // head 4: 9 floats, 36B stride -> only 4B aligned, scalar
        float v4[9];
        #pragma unroll
        for (int j = 0; j < 9; ++j) v4[j] = o4[i * 9 + j];
        // labels: 29 floats, 116B stride -> 4B aligned, scalar
        float lv[29];
        #pragma unroll
        for (int j = 0; j < 29; ++j) lv[j] = lbl[i * 29 + j];

        loss  = head_loss(v1, 8, lv + 0);
        loss += head_loss(v2, 6, lv + 8);
        loss += head_loss(v3, 6, lv + 14);
        loss += head_loss(v4, 9, lv + 20);
    }

    // reduce: wave64 shfl in double -> LDS -> one double atomic per block
    double d = (double)loss;
    #pragma unroll
    for (int off = 32; off > 0; off >>= 1) d += __shfl_down(d, off);

    __shared__ double sacc[4];
    const int wid = threadIdx.x >> 6;
    const int lane = threadIdx.x & 63;
    if (lane == 0) sacc[wid] = d;
    __syncthreads();
    if (threadIdx.x == 0) {
        double t = sacc[0] + sacc[1] + sacc[2] + sacc[3];
        atomicAdd(acc_out, t);
    }
}

__global__ void finalize_kernel(const double* __restrict__ acc, float* __restrict__ out) {
    out[0] = (float)(acc[0] / (double)NROWS);
}

extern "C" void kernel_launch(void* const* d_in, const int* in_sizes, int n_in,
                              void* d_out, int out_size, void* d_ws, size_t ws_size,
                              hipStream_t stream) {
    const float* o1  = (const float*)d_in[0];
    const float* o2  = (const float*)d_in[1];
    const float* o3  = (const float*)d_in[2];
    const float* o4  = (const float*)d_in[3];
    const float* lbl = (const float*)d_in[4];
    double* acc = (double*)d_ws;

    hipMemsetAsync(acc, 0, sizeof(double), stream);
    fused_loss_kernel<<<NROWS / 256, 256, 0, stream>>>(o1, o2, o3, o4, lbl, acc);
    finalize_kernel<<<1, 1, 0, stream>>>(acc, (float*)d_out);
}

// Round 2
// 28.697 us; speedup vs baseline: 1.5348x; 1.5348x over previous
//
#include <hip/hip_runtime.h>
#include <cmath>

#define NROWS 524288
#define NBLOCKS (NROWS / 256)
#define EPS 1e-10f

template <int N>
__device__ __forceinline__ float head_loss(const float* x, const float* lbl) {
    float m = -INFINITY;
    #pragma unroll
    for (int i = 0; i < N; ++i) m = fmaxf(m, x[i]);
    float e[N];
    float s = 0.f;
    #pragma unroll
    for (int i = 0; i < N; ++i) { e[i] = __expf(x[i] - m); s += e[i]; }
    float inv = 1.0f / s;
    float acc = 0.f;
    #pragma unroll
    for (int i = 0; i < N; ++i) acc += __logf(e[i] * inv + EPS) * lbl[i];
    return -acc;
}

__global__ __launch_bounds__(256) void fused_loss_kernel(
    const float* __restrict__ o1, const float* __restrict__ o2,
    const float* __restrict__ o3, const float* __restrict__ o4,
    const float* __restrict__ lbl, double* __restrict__ partial) {
    __shared__ float slbl[256 * 29];   // 29696 B
    __shared__ float so4[256 * 9];     //  9216 B
    __shared__ double sacc[4];

    const int tid = threadIdx.x;
    const size_t blk = blockIdx.x;

    // Cooperative coalesced staging. Block bases are 16B-aligned:
    // labels: 29696 B/block, o4: 9216 B/block (both % 16 == 0).
    {
        const float4* src = reinterpret_cast<const float4*>(lbl + blk * (256 * 29));
        float4* dst = reinterpret_cast<float4*>(slbl);
        #pragma unroll
        for (int k = 0; k < 7; ++k) dst[tid + k * 256] = src[tid + k * 256];
        if (tid < 1856 - 7 * 256) dst[tid + 7 * 256] = src[tid + 7 * 256];
    }
    {
        const float4* src = reinterpret_cast<const float4*>(o4 + blk * (256 * 9));
        float4* dst = reinterpret_cast<float4*>(so4);
        #pragma unroll
        for (int k = 0; k < 2; ++k) dst[tid + k * 256] = src[tid + k * 256];
        if (tid < 576 - 2 * 256) dst[tid + 2 * 256] = src[tid + 2 * 256];
    }
    __syncthreads();

    const size_t i = blk * 256 + tid;

    // head 1: 8 floats, 32B stride, 16B aligned -> two float4
    float v1[8];
    {
        const float4* p = reinterpret_cast<const float4*>(o1 + i * 8);
        float4 a = p[0], b = p[1];
        v1[0] = a.x; v1[1] = a.y; v1[2] = a.z; v1[3] = a.w;
        v1[4] = b.x; v1[5] = b.y; v1[6] = b.z; v1[7] = b.w;
    }
    // heads 2,3: 6 floats, 24B stride, 8B aligned -> three float2
    float v2[6], v3[6];
    {
        const float2* p = reinterpret_cast<const float2*>(o2 + i * 6);
        float2 a = p[0], b = p[1], c = p[2];
        v2[0] = a.x; v2[1] = a.y; v2[2] = b.x; v2[3] = b.y; v2[4] = c.x; v2[5] = c.y;
    }
    {
        const float2* p = reinterpret_cast<const float2*>(o3 + i * 6);
        float2 a = p[0], b = p[1], c = p[2];
        v3[0] = a.x; v3[1] = a.y; v3[2] = b.x; v3[3] = b.y; v3[4] = c.x; v3[5] = c.y;
    }

    const float* lrow = slbl + tid * 29;  // stride 29 (odd) -> 2-way bank alias, free
    const float* orow = so4 + tid * 9;    // stride 9 (odd)  -> free

    float loss;
    loss  = head_loss<8>(v1, lrow + 0);
    loss += head_loss<6>(v2, lrow + 8);
    loss += head_loss<6>(v3, lrow + 14);
    loss += head_loss<9>(orow, lrow + 20);

    // wave64 shfl reduce in double -> LDS -> per-block partial (no atomics)
    double d = (double)loss;
    #pragma unroll
    for (int off = 32; off > 0; off >>= 1) d += __shfl_down(d, off);

    const int wid = tid >> 6;
    const int lane = tid & 63;
    if (lane == 0) sacc[wid] = d;
    __syncthreads();
    if (tid == 0) partial[blk] = sacc[0] + sacc[1] + sacc[2] + sacc[3];
}

__global__ __launch_bounds__(256) void reduce_kernel(const double* __restrict__ partial,
                                                     float* __restrict__ out) {
    double s = 0.0;
    for (int i = threadIdx.x; i < NBLOCKS; i += 256) s += partial[i];
    #pragma unroll
    for (int off = 32; off > 0; off >>= 1) s += __shfl_down(s, off);
    __shared__ double sa[4];
    const int wid = threadIdx.x >> 6;
    if ((threadIdx.x & 63) == 0) sa[wid] = s;
    __syncthreads();
    if (threadIdx.x == 0) out[0] = (float)((sa[0] + sa[1] + sa[2] + sa[3]) / (double)NROWS);
}

extern "C" void kernel_launch(void* const* d_in, const int* in_sizes, int n_in,
                              void* d_out, int out_size, void* d_ws, size_t ws_size,
                              hipStream_t stream) {
    const float* o1  = (const float*)d_in[0];
    const float* o2  = (const float*)d_in[1];
    const float* o3  = (const float*)d_in[2];
    const float* o4  = (const float*)d_in[3];
    const float* lbl = (const float*)d_in[4];
    double* partial = (double*)d_ws;  // NBLOCKS doubles, fully overwritten each call

    fused_loss_kernel<<<NBLOCKS, 256, 0, stream>>>(o1, o2, o3, o4, lbl, partial);
    reduce_kernel<<<1, 256, 0, stream>>>(partial, (float*)d_out);
}

// Round 3
// 28.696 us; speedup vs baseline: 1.5349x; 1.0000x over previous
//
#include <hip/hip_runtime.h>
#include <cmath>

#define NROWS 524288
#define NBLOCKS (NROWS / 256)
#define EPS 1e-10f

template <int N>
__device__ __forceinline__ float head_loss(const float* x, const float* lbl) {
    float m = -INFINITY;
    #pragma unroll
    for (int i = 0; i < N; ++i) m = fmaxf(m, x[i]);
    float e[N];
    float s = 0.f;
    #pragma unroll
    for (int i = 0; i < N; ++i) { e[i] = __expf(x[i] - m); s += e[i]; }
    float inv = 1.0f / s;
    float acc = 0.f;
    #pragma unroll
    for (int i = 0; i < N; ++i) acc += __logf(e[i] * inv + EPS) * lbl[i];
    return -acc;
}

// LDS: labels only (29 floats/row) -> 29696 B/block -> 5 blocks/CU (20 waves, 62.5%)
__global__ __launch_bounds__(256, 5) void fused_loss_kernel(
    const float* __restrict__ o1, const float* __restrict__ o2,
    const float* __restrict__ o3, const float* __restrict__ o4,
    const float* __restrict__ lbl, double* __restrict__ partial) {
    __shared__ float slbl[256 * 29];   // 29696 B
    __shared__ double sacc[4];

    const int tid = threadIdx.x;
    const int wid = tid >> 6;
    const int lane = tid & 63;
    const size_t blk = blockIdx.x;

    // Wave-private label staging: wave w stages exactly its own 64 rows
    // (464 float4 = 7424 B, 16B-aligned), so no __syncthreads is needed —
    // in-wave LDS ordering (lgkmcnt) guarantees read-after-write.
    {
        const float4* src = reinterpret_cast<const float4*>(lbl + blk * (256 * 29)) + wid * 464;
        float4* dst = reinterpret_cast<float4*>(slbl) + wid * 464;
        #pragma unroll
        for (int k = 0; k < 7; ++k) dst[lane + 64 * k] = src[lane + 64 * k];
        if (lane < 16) dst[lane + 448] = src[lane + 448];  // 464 = 7*64 + 16
    }

    const size_t i = blk * 256 + tid;

    // head 1: 8 floats, 32B stride, 16B aligned -> two float4
    float v1[8];
    {
        const float4* p = reinterpret_cast<const float4*>(o1 + i * 8);
        float4 a = p[0], b = p[1];
        v1[0] = a.x; v1[1] = a.y; v1[2] = a.z; v1[3] = a.w;
        v1[4] = b.x; v1[5] = b.y; v1[6] = b.z; v1[7] = b.w;
    }
    // heads 2,3: 6 floats, 24B stride, 8B aligned -> three float2
    float v2[6], v3[6];
    {
        const float2* p = reinterpret_cast<const float2*>(o2 + i * 6);
        float2 a = p[0], b = p[1], c = p[2];
        v2[0] = a.x; v2[1] = a.y; v2[2] = b.x; v2[3] = b.y; v2[4] = c.x; v2[5] = c.y;
    }
    {
        const float2* p = reinterpret_cast<const float2*>(o3 + i * 6);
        float2 a = p[0], b = p[1], c = p[2];
        v3[0] = a.x; v3[1] = a.y; v3[2] = b.x; v3[3] = b.y; v3[4] = c.x; v3[5] = c.y;
    }
    // head 4: 9 floats, 36B stride -> scalar loads (each 64B line fully used
    // across the wave's lanes; latency hidden by 62.5% occupancy)
    float v4[9];
    {
        const float* p = o4 + i * 9;
        #pragma unroll
        for (int j = 0; j < 9; ++j) v4[j] = p[j];
    }

    const float* lrow = slbl + tid * 29;  // stride 29 (odd): 2-way bank alias, free

    float loss;
    loss  = head_loss<8>(v1, lrow + 0);
    loss += head_loss<6>(v2, lrow + 8);
    loss += head_loss<6>(v3, lrow + 14);
    loss += head_loss<9>(v4, lrow + 20);

    // wave64 shfl reduce in double -> LDS -> per-block partial (no atomics)
    double d = (double)loss;
    #pragma unroll
    for (int off = 32; off > 0; off >>= 1) d += __shfl_down(d, off);

    if (lane == 0) sacc[wid] = d;
    __syncthreads();
    if (tid == 0) partial[blk] = sacc[0] + sacc[1] + sacc[2] + sacc[3];
}

__global__ __launch_bounds__(256) void reduce_kernel(const double* __restrict__ partial,
                                                     float* __restrict__ out) {
    double s = 0.0;
    for (int i = threadIdx.x; i < NBLOCKS; i += 256) s += partial[i];
    #pragma unroll
    for (int off = 32; off > 0; off >>= 1) s += __shfl_down(s, off);
    __shared__ double sa[4];
    const int wid = threadIdx.x >> 6;
    if ((threadIdx.x & 63) == 0) sa[wid] = s;
    __syncthreads();
    if (threadIdx.x == 0) out[0] = (float)((sa[0] + sa[1] + sa[2] + sa[3]) / (double)NROWS);
}

extern "C" void kernel_launch(void* const* d_in, const int* in_sizes, int n_in,
                              void* d_out, int out_size, void* d_ws, size_t ws_size,
                              hipStream_t stream) {
    const float* o1  = (const float*)d_in[0];
    const float* o2  = (const float*)d_in[1];
    const float* o3  = (const float*)d_in[2];
    const float* o4  = (const float*)d_in[3];
    const float* lbl = (const float*)d_in[4];
    double* partial = (double*)d_ws;  // NBLOCKS doubles, fully overwritten each call

    fused_loss_kernel<<<NBLOCKS, 256, 0, stream>>>(o1, o2, o3, o4, lbl, partial);
    reduce_kernel<<<1, 256, 0, stream>>>(partial, (float*)d_out);
}